// Round 10
// baseline (401.534 us; speedup 1.0000x reference)
//
#include <hip/hip_runtime.h>
#include <math.h>

static constexpr int Bsz  = 16;
static constexpr int Npts = 2048;
static constexpr int C1 = 64, C2 = 128, C3 = 1024;
static constexpr int NBINS = 73;
static constexpr int NROWS = Bsz * C3;          // 16384
static constexpr int TOTAL = NBINS * NROWS;     // 1196032
static constexpr float VMINf = -10.0f;
static constexpr float TOTAL_MAXf = 327670.0f;  // 20*16384 - 10

typedef __attribute__((ext_vector_type(8))) short short8v;
typedef __attribute__((ext_vector_type(4))) float f32x4;

__device__ __forceinline__ float bnrelu(float x, float m, float inv, float g, float be) {
    float t = ((x - m) * inv) * g + be;
    return t > 0.0f ? t : 0.0f;
}

// fp32 -> bf16 round-to-nearest-even (bit formula, matches HW RNE)
__device__ __forceinline__ ushort f2bf(float f) {
    uint u = __float_as_uint(f);
    return (ushort)((u + 0x7FFFu + ((u >> 16) & 1u)) >> 16);
}

// ---------------- conv1: [16,3,2048] -> [16,64,2048] (pre-BN, bias added), float4 ----------------
__global__ __launch_bounds__(256)
void conv1_kernel(const float* __restrict__ x, const float* __restrict__ w,
                  const float* __restrict__ bias, float* __restrict__ out) {
    __shared__ float ws[C1 * 3];
    __shared__ float bs[C1];
    int tid = threadIdx.x;
    if (tid < C1 * 3) ws[tid] = w[tid];
    if (tid < C1) bs[tid] = bias[tid];
    __syncthreads();
    int p = blockIdx.x * 256 + tid;        // quad index, total 16*512 = 8192
    int b = p >> 9;
    int nq = p & 511;
    const float* xb = x + (size_t)b * 3 * Npts;
    float4 x0 = ((const float4*)xb)[nq];
    float4 x1 = ((const float4*)(xb + Npts))[nq];
    float4 x2 = ((const float4*)(xb + 2 * Npts))[nq];
    float* o = out + (size_t)b * C1 * Npts + nq * 4;
    #pragma unroll
    for (int c = 0; c < C1; ++c) {
        float w0 = ws[c * 3], w1 = ws[c * 3 + 1], w2 = ws[c * 3 + 2], bv = bs[c];
        float4 r;
        r.x = fmaf(w0, x0.x, fmaf(w1, x1.x, fmaf(w2, x2.x, bv)));
        r.y = fmaf(w0, x0.y, fmaf(w1, x1.y, fmaf(w2, x2.y, bv)));
        r.z = fmaf(w0, x0.z, fmaf(w1, x1.z, fmaf(w2, x2.z, bv)));
        r.w = fmaf(w0, x0.w, fmaf(w1, x1.w, fmaf(w2, x2.w, bv)));
        *(float4*)(o + (size_t)c * Npts) = r;
    }
}

// ---------------- partial stats for h1: grid = C1*4 blocks, f64 atomics ----------------
__global__ __launch_bounds__(256)
void stats_partial_kernel(const float* __restrict__ in,
                          double* __restrict__ sum, double* __restrict__ sumsq) {
    int c = blockIdx.x >> 2;
    int qb = blockIdx.x & 3;
    int tid = threadIdx.x;
    double s = 0.0, q = 0.0;
    for (int bb = qb * 4; bb < qb * 4 + 4; ++bb) {
        const float4* p = (const float4*)(in + ((size_t)bb * C1 + c) * Npts);
        for (int n = tid; n < Npts / 4; n += 256) {
            float4 v = p[n];
            double a0 = v.x, a1 = v.y, a2 = v.z, a3 = v.w;
            s += a0 + a1 + a2 + a3;
            q += a0 * a0 + a1 * a1 + a2 * a2 + a3 * a3;
        }
    }
    __shared__ double sh_s[256];
    __shared__ double sh_q[256];
    sh_s[tid] = s; sh_q[tid] = q;
    __syncthreads();
    for (int off = 128; off > 0; off >>= 1) {
        if (tid < off) { sh_s[tid] += sh_s[tid + off]; sh_q[tid] += sh_q[tid + off]; }
        __syncthreads();
    }
    if (tid == 0) {
        unsafeAtomicAdd(&sum[c], sh_s[0]);
        unsafeAtomicAdd(&sumsq[c], sh_q[0]);
    }
}

// ---------------- finalize: (sum, sumsq) -> (mean, rsqrt(var+eps)) ----------------
__global__ __launch_bounds__(256)
void finalize_stats_kernel(const double* __restrict__ s, const double* __restrict__ q, int C,
                           float* __restrict__ mout, float* __restrict__ iout) {
    int c = blockIdx.x * 256 + threadIdx.x;
    if (c >= C) return;
    double cnt = (double)Bsz * (double)Npts;
    double m = s[c] / cnt;
    double var = q[c] / cnt - m * m;
    mout[c] = (float)m;
    iout[c] = (float)(1.0 / sqrt(var + 1e-5));
}

// ---------------- 64x64 tiled conv2 (fp32), BN+ReLU on input, fused output stats ----------------
template<int CIN, int COUT>
__global__ __launch_bounds__(256)
void conv_bn_64(const float* __restrict__ in, const float* __restrict__ W,
                const float* __restrict__ bias,
                const float* __restrict__ m, const float* __restrict__ inv,
                const float* __restrict__ g, const float* __restrict__ be,
                float* __restrict__ out,
                double* __restrict__ sum, double* __restrict__ sumsq) {
    constexpr int KT = 32;
    __shared__ float Ws[KT][64];
    __shared__ float Xs[KT][64];
    int tid = threadIdx.x;
    int nBase = blockIdx.x * 64;
    int oBase = blockIdx.y * 64;
    int b = blockIdx.z;
    int ty = tid / 16, tx = tid % 16;
    float acc[4][4] = {};

    int w_o  = tid / 4;
    int w_k0 = (tid % 4) * 8;
    int x_c  = tid / 8;
    int x_n0 = (tid % 8) * 8;

    for (int kBase = 0; kBase < CIN; kBase += KT) {
        const float* wp = W + (size_t)(oBase + w_o) * CIN + kBase + w_k0;
        float4 wa = *(const float4*)wp;
        float4 wb = *(const float4*)(wp + 4);
        float wv[8] = {wa.x, wa.y, wa.z, wa.w, wb.x, wb.y, wb.z, wb.w};
        #pragma unroll
        for (int i = 0; i < 8; ++i) Ws[w_k0 + i][w_o] = wv[i];

        int c = kBase + x_c;
        float mm = m[c], ii = inv[c], gg = g[c], bb = be[c];
        const float* xp = in + ((size_t)b * CIN + c) * Npts + nBase + x_n0;
        float4 xa = *(const float4*)xp;
        float4 xb = *(const float4*)(xp + 4);
        float xv[8] = {xa.x, xa.y, xa.z, xa.w, xb.x, xb.y, xb.z, xb.w};
        #pragma unroll
        for (int i = 0; i < 8; ++i) Xs[x_c][x_n0 + i] = bnrelu(xv[i], mm, ii, gg, bb);

        __syncthreads();
        #pragma unroll
        for (int kk = 0; kk < KT; ++kk) {
            float4 w4 = *(const float4*)(&Ws[kk][ty * 4]);
            float4 x4 = *(const float4*)(&Xs[kk][tx * 4]);
            float wr[4] = {w4.x, w4.y, w4.z, w4.w};
            float xr[4] = {x4.x, x4.y, x4.z, x4.w};
            #pragma unroll
            for (int i = 0; i < 4; ++i)
                #pragma unroll
                for (int j = 0; j < 4; ++j)
                    acc[i][j] = fmaf(wr[i], xr[j], acc[i][j]);
        }
        __syncthreads();
    }

    #pragma unroll
    for (int i = 0; i < 4; ++i) {
        int o = oBase + ty * 4 + i;
        float bv = bias[o];
        float v[4] = {acc[i][0] + bv, acc[i][1] + bv, acc[i][2] + bv, acc[i][3] + bv};
        *(float4*)(out + ((size_t)b * COUT + o) * Npts + nBase + tx * 4) =
            make_float4(v[0], v[1], v[2], v[3]);
        double si = 0.0, qi = 0.0;
        #pragma unroll
        for (int j = 0; j < 4; ++j) { double dv = (double)v[j]; si += dv; qi += dv * dv; }
        #pragma unroll
        for (int off = 1; off < 16; off <<= 1) {
            si += __shfl_xor(si, off, 64);
            qi += __shfl_xor(qi, off, 64);
        }
        if (tx == 0) {
            unsafeAtomicAdd(&sum[o], si);
            unsafeAtomicAdd(&sumsq[o], qi);
        }
    }
}

// ---------------- h2 fp32 [b][c][n] -> h2t bf16 [b][n][c], applying bn2+relu ----------------
__global__ __launch_bounds__(256)
void transpose_bnrelu_kernel(const float* __restrict__ in,
                             const float* __restrict__ m, const float* __restrict__ inv,
                             const float* __restrict__ g, const float* __restrict__ be,
                             ushort* __restrict__ out) {
    __shared__ ushort Ls[C2 * 72];   // [c][n] tile, 64 n cols, pad to 72
    __shared__ float pm[C2], pi[C2], pg[C2], pb[C2];
    int tid = threadIdx.x;
    int n0 = blockIdx.x * 64;
    int b = blockIdx.y;
    if (tid < C2) { pm[tid] = m[tid]; pi[tid] = inv[tid]; pg[tid] = g[tid]; pb[tid] = be[tid]; }
    __syncthreads();
    #pragma unroll
    for (int it = 0; it < 8; ++it) {
        int q = it * 256 + tid;            // 2048 quads = 128c x 16 quad-cols
        int c = q >> 4, nq = q & 15;
        float4 v = *(const float4*)(in + ((size_t)b * C2 + c) * Npts + n0 + nq * 4);
        float mm = pm[c], ii = pi[c], gg = pg[c], bb = pb[c];
        uint lo = (uint)f2bf(bnrelu(v.x, mm, ii, gg, bb)) |
                  ((uint)f2bf(bnrelu(v.y, mm, ii, gg, bb)) << 16);
        uint hi = (uint)f2bf(bnrelu(v.z, mm, ii, gg, bb)) |
                  ((uint)f2bf(bnrelu(v.w, mm, ii, gg, bb)) << 16);
        *(uint2*)(&Ls[c * 72 + nq * 4]) = make_uint2(lo, hi);
    }
    __syncthreads();
    int n = tid >> 2, cs = (tid & 3) * 32;
    uint w[16];
    #pragma unroll
    for (int j = 0; j < 16; ++j) {
        w[j] = (uint)Ls[(cs + 2 * j) * 72 + n] | ((uint)Ls[(cs + 2 * j + 1) * 72 + n] << 16);
    }
    ushort* op = out + ((size_t)b * Npts + n0 + n) * C2 + cs;
    *(uint4*)(op)      = make_uint4(w[0],  w[1],  w[2],  w[3]);
    *(uint4*)(op + 8)  = make_uint4(w[4],  w[5],  w[6],  w[7]);
    *(uint4*)(op + 16) = make_uint4(w[8],  w[9],  w[10], w[11]);
    *(uint4*)(op + 24) = make_uint4(w[12], w[13], w[14], w[15]);
}

// ---------------- conv3 via bf16 MFMA: h2t [b][n][128] x w3 [1024][128] -> h3 bf16 ----------------
// Tile: 64 o x 128 n, K=128 fully in LDS (one barrier). 4 waves split n (32 each).
// 16x16x32 layouts: A lane l -> row l&15, k (l>>4)*8+j ; B lane l -> col l&15, same k;
// D lane l -> col l&15, row (l>>4)*4+reg   [m89-verified]
__global__ __launch_bounds__(256)
void conv3_mfma_kernel(const ushort* __restrict__ xt, const float* __restrict__ W,
                       const float* __restrict__ bias, ushort* __restrict__ out,
                       double* __restrict__ sum, double* __restrict__ sumsq) {
    constexpr int LDW = 136;                 // 128 + 8 bf16 pad (keeps 16B alignment)
    __shared__ ushort Wl[64 * LDW];          // 17 KB
    __shared__ ushort Xl[128 * LDW];         // 34 KB
    const int tid = threadIdx.x;
    const int nBase = blockIdx.x * 128;
    const int oBase = blockIdx.y * 64;
    const int b = blockIdx.z;

    // stage W slice (64 x 128 fp32 -> bf16)
    #pragma unroll
    for (int it = 0; it < 8; ++it) {
        int q = it * 256 + tid;              // 2048 quads
        int r = q >> 5, cq = q & 31;
        float4 v = *(const float4*)(W + (size_t)(oBase + r) * C2 + cq * 4);
        uint lo = (uint)f2bf(v.x) | ((uint)f2bf(v.y) << 16);
        uint hi = (uint)f2bf(v.z) | ((uint)f2bf(v.w) << 16);
        *(uint2*)(&Wl[r * LDW + cq * 4]) = make_uint2(lo, hi);
    }
    // stage X slice (128 n-rows x 128 k, contiguous 32KB in h2t)
    const ushort* xb = xt + ((size_t)b * Npts + nBase) * C2;
    #pragma unroll
    for (int it = 0; it < 8; ++it) {
        int o8 = it * 256 + tid;             // 2048 octets
        int r = o8 >> 4, c8 = o8 & 15;
        uint4 v = *(const uint4*)(xb + (size_t)r * C2 + c8 * 8);
        *(uint4*)(&Xl[r * LDW + c8 * 8]) = v;
    }
    __syncthreads();

    const int wv = tid >> 6, lane = tid & 63, lr = lane & 15, lg = lane >> 4;
    f32x4 acc[4][2];
    #pragma unroll
    for (int i = 0; i < 4; ++i) {
        #pragma unroll
        for (int j = 0; j < 2; ++j) { f32x4 z = {0.f, 0.f, 0.f, 0.f}; acc[i][j] = z; }
    }

    #pragma unroll
    for (int ks = 0; ks < 4; ++ks) {
        const int ko = ks * 32 + lg * 8;
        short8v b0 = *(const short8v*)(&Xl[(wv * 32 + lr) * LDW + ko]);
        short8v b1 = *(const short8v*)(&Xl[(wv * 32 + 16 + lr) * LDW + ko]);
        #pragma unroll
        for (int fo = 0; fo < 4; ++fo) {
            short8v a = *(const short8v*)(&Wl[(fo * 16 + lr) * LDW + ko]);
            acc[fo][0] = __builtin_amdgcn_mfma_f32_16x16x32_bf16(a, b0, acc[fo][0], 0, 0, 0);
            acc[fo][1] = __builtin_amdgcn_mfma_f32_16x16x32_bf16(a, b1, acc[fo][1], 0, 0, 0);
        }
    }

    #pragma unroll
    for (int fo = 0; fo < 4; ++fo) {
        #pragma unroll
        for (int rg = 0; rg < 4; ++rg) {
            int o = oBase + fo * 16 + lg * 4 + rg;
            float bv = bias[o];
            float v0 = acc[fo][0][rg] + bv;
            float v1 = acc[fo][1][rg] + bv;
            size_t rowoff = ((size_t)b * C3 + o) * Npts + nBase + wv * 32;
            out[rowoff + lr]      = f2bf(v0);
            out[rowoff + 16 + lr] = f2bf(v1);
            double s  = (double)v0 + (double)v1;
            double qq = (double)v0 * v0 + (double)v1 * v1;
            #pragma unroll
            for (int off = 1; off < 16; off <<= 1) {
                s  += __shfl_xor(s,  off, 64);
                qq += __shfl_xor(qq, off, 64);
            }
            if (lr == 0) {
                unsafeAtomicAdd(&sum[o],   s);
                unsafeAtomicAdd(&sumsq[o], qq);
            }
        }
    }
}

// ---------------- histogram (bf16 input): wave-private bins, lazy zero counting ----------------
__global__ __launch_bounds__(256)
void hist_kernel(const ushort* __restrict__ h3,
                 const float* __restrict__ m, const float* __restrict__ inv,
                 const float* __restrict__ g, const float* __restrict__ be,
                 unsigned* __restrict__ counts) {
    __shared__ unsigned bins[4][80];
    int row = blockIdx.x;                   // b*C3 + f
    int f = row & (C3 - 1);
    int tid = threadIdx.x;
    int wv = tid >> 6;
    for (int i = tid; i < 4 * 80; i += 256) ((unsigned*)bins)[i] = 0u;
    __syncthreads();
    float mm = m[f], ii = inv[f], gg = g[f], bb = be[f];
    float off = 20.0f * (float)row;
    const uint4* p4 = (const uint4*)(h3 + (size_t)row * Npts);   // 256 uint4 per row
    const float WIDTH = (float)(327680.0 / 1196032.0);
    int rbase = row * NBINS;
    int zc = 0;
    uint4 q = p4[tid];                      // 8 bf16 per thread, single pass
    uint wsv[4] = {q.x, q.y, q.z, q.w};
    #pragma unroll
    for (int j = 0; j < 4; ++j) {
        float vlo = __uint_as_float(wsv[j] << 16);
        float vhi = __uint_as_float(wsv[j] & 0xFFFF0000u);
        float pair[2] = {vlo, vhi};
        #pragma unroll
        for (int h = 0; h < 2; ++h) {
            float v = bnrelu(pair[h], mm, ii, gg, bb);
            if (v == 0.0f) { ++zc; continue; }
            float flat = v + off;
            if (flat >= VMINf && flat <= TOTAL_MAXf) {
                int idx = (int)floorf((flat - VMINf) / WIDTH);
                if (idx > TOTAL - 1) idx = TOTAL - 1;
                if (idx < 0) idx = 0;
                int local = idx - rbase;
                if (local >= 0 && local < NBINS) atomicAdd(&bins[wv][local], 1u);
                else atomicAdd(&counts[idx], 1u);
            }
        }
    }
    #pragma unroll
    for (int o = 32; o >= 1; o >>= 1) zc += __shfl_xor(zc, o, 64);
    if ((tid & 63) == 0 && zc) atomicAdd(&bins[wv][36], (unsigned)zc);
    __syncthreads();
    if (tid < NBINS) {
        unsigned t = bins[0][tid] + bins[1][tid] + bins[2][tid] + bins[3][tid];
        if (t) atomicAdd(&counts[rbase + tid], t);
    }
}

// ---------------- per-row first-max argmax -> feat ----------------
__global__ __launch_bounds__(256)
void argmax_kernel(const unsigned* __restrict__ counts, float* __restrict__ feat) {
    int row = blockIdx.x * 256 + threadIdx.x;
    if (row >= NROWS) return;
    const unsigned* c = counts + (size_t)row * NBINS;
    unsigned best = c[0]; int bi = 0;
    #pragma unroll 8
    for (int i = 1; i < NBINS; ++i) {
        unsigned v = c[i];
        if (v > best) { best = v; bi = i; }
    }
    feat[row] = (float)bi;
}

// ---------------- FC + batch-BN + ReLU (one block per output feature) ----------------
template<int K, int COUT>
__global__ __launch_bounds__(256)
void fc_bn_relu_kernel(const float* __restrict__ in, const float* __restrict__ W,
                       const float* __restrict__ bias,
                       const float* __restrict__ g, const float* __restrict__ be,
                       float* __restrict__ out) {
    int j = blockIdx.x;
    int tid = threadIdx.x;
    int b = tid / 16;
    int l = tid % 16;
    const float* wrow = W + (size_t)j * K;
    const float* xrow = in + (size_t)b * K;
    float s = 0.0f;
    for (int k = l; k < K; k += 16) s = fmaf(xrow[k], wrow[k], s);
    #pragma unroll
    for (int o = 8; o >= 1; o >>= 1) s += __shfl_xor(s, o, 64);
    __shared__ float vals[Bsz];
    __shared__ float stat[2];
    if (l == 0) vals[b] = s + bias[j];
    __syncthreads();
    if (tid == 0) {
        double a = 0.0, q = 0.0;
        for (int i = 0; i < Bsz; ++i) { double v = vals[i]; a += v; q += v * v; }
        double mm = a / Bsz;
        double var = q / Bsz - mm * mm;
        stat[0] = (float)mm;
        stat[1] = (float)(1.0 / sqrt(var + 1e-5));
    }
    __syncthreads();
    if (tid < Bsz) {
        float t = ((vals[tid] - stat[0]) * stat[1]) * g[j] + be[j];
        out[(size_t)tid * COUT + j] = t > 0.0f ? t : 0.0f;
    }
}

// ---------------- fc3 + identity ----------------
__global__ __launch_bounds__(256)
void fc3_kernel(const float* __restrict__ in, const float* __restrict__ W,
                const float* __restrict__ bias, float* __restrict__ out) {
    int t = threadIdx.x;
    if (t >= Bsz * 9) return;
    int b = t / 9, j = t % 9;
    const float* x = in + (size_t)b * 256;
    const float* w = W + (size_t)j * 256;
    float s = 0.0f;
    for (int k = 0; k < 256; ++k) s = fmaf(x[k], w[k], s);
    s += bias[j];
    if (j == 0 || j == 4 || j == 8) s += 1.0f;
    out[t] = s;
}

extern "C" void kernel_launch(void* const* d_in, const int* in_sizes, int n_in,
                              void* d_out, int out_size, void* d_ws, size_t ws_size,
                              hipStream_t stream) {
    const float* x   = (const float*)d_in[0];
    const float* w1  = (const float*)d_in[1];
    const float* b1  = (const float*)d_in[2];
    const float* g1  = (const float*)d_in[3];
    const float* be1 = (const float*)d_in[4];
    const float* w2  = (const float*)d_in[5];
    const float* b2  = (const float*)d_in[6];
    const float* g2  = (const float*)d_in[7];
    const float* be2 = (const float*)d_in[8];
    const float* w3  = (const float*)d_in[9];
    const float* b3  = (const float*)d_in[10];
    const float* g3  = (const float*)d_in[11];
    const float* be3 = (const float*)d_in[12];
    const float* fw1 = (const float*)d_in[13];
    const float* fb1 = (const float*)d_in[14];
    const float* g4  = (const float*)d_in[15];
    const float* be4 = (const float*)d_in[16];
    const float* fw2 = (const float*)d_in[17];
    const float* fb2 = (const float*)d_in[18];
    const float* g5  = (const float*)d_in[19];
    const float* be5 = (const float*)d_in[20];
    const float* fw3 = (const float*)d_in[21];
    const float* fb3 = (const float*)d_in[22];

    // workspace: [f64 accumulators][u32 counts][f32 tensors][bf16 tensors]
    double* sum1 = (double*)d_ws;                       // 64
    double* q1d  = sum1 + C1;
    double* sum2 = q1d + C1;                            // 128
    double* q2   = sum2 + C2;
    double* sum3 = q2 + C2;                             // 1024
    double* q3   = sum3 + C3;
    unsigned* counts = (unsigned*)(q3 + C3);            // 1,196,032
    float* h1 = (float*)(counts + TOTAL);               // 16*64*2048 f32
    float* h2 = h1 + (size_t)Bsz * C1 * Npts;           // 16*128*2048 f32
    float* m1 = h2 + (size_t)Bsz * C2 * Npts;
    float* i1 = m1 + C1;
    float* m2 = i1 + C1;
    float* i2 = m2 + C2;
    float* m3 = i2 + C2;
    float* i3 = m3 + C3;
    float* feat = i3 + C3;                              // 16,384
    float* h4 = feat + NROWS;
    float* h5 = h4 + Bsz * 512;
    ushort* h2t = (ushort*)(h5 + Bsz * 256);            // 16*2048*128 bf16
    ushort* h3  = h2t + (size_t)Bsz * Npts * C2;        // 16*1024*2048 bf16

    size_t zero_bytes = (size_t)(2 * C1 + 2 * C2 + 2 * C3) * sizeof(double)
                      + (size_t)TOTAL * sizeof(unsigned);
    hipMemsetAsync(d_ws, 0, zero_bytes, stream);

    conv1_kernel<<<dim3(Bsz * Npts / 4 / 256), 256, 0, stream>>>(x, w1, b1, h1);
    stats_partial_kernel<<<dim3(C1 * 4), 256, 0, stream>>>(h1, sum1, q1d);
    finalize_stats_kernel<<<dim3(1), 256, 0, stream>>>(sum1, q1d, C1, m1, i1);
    conv_bn_64<C1, C2><<<dim3(Npts / 64, C2 / 64, Bsz), 256, 0, stream>>>(
        h1, w2, b2, m1, i1, g1, be1, h2, sum2, q2);
    finalize_stats_kernel<<<dim3(1), 256, 0, stream>>>(sum2, q2, C2, m2, i2);
    transpose_bnrelu_kernel<<<dim3(Npts / 64, Bsz), 256, 0, stream>>>(
        h2, m2, i2, g2, be2, h2t);
    conv3_mfma_kernel<<<dim3(Npts / 128, C3 / 64, Bsz), 256, 0, stream>>>(
        h2t, w3, b3, h3, sum3, q3);
    finalize_stats_kernel<<<dim3(C3 / 256), 256, 0, stream>>>(sum3, q3, C3, m3, i3);
    hist_kernel<<<dim3(NROWS), 256, 0, stream>>>(h3, m3, i3, g3, be3, counts);
    argmax_kernel<<<dim3(NROWS / 256), 256, 0, stream>>>(counts, feat);
    fc_bn_relu_kernel<1024, 512><<<dim3(512), 256, 0, stream>>>(feat, fw1, fb1, g4, be4, h4);
    fc_bn_relu_kernel<512, 256><<<dim3(256), 256, 0, stream>>>(h4, fw2, fb2, g5, be5, h5);
    fc3_kernel<<<dim3(1), 256, 0, stream>>>(h5, fw3, fb3, (float*)d_out);
}

// Round 14
// 298.013 us; speedup vs baseline: 1.3474x; 1.3474x over previous
//
#include <hip/hip_runtime.h>
#include <math.h>

static constexpr int Bsz  = 16;
static constexpr int Npts = 2048;
static constexpr int C1 = 64, C2 = 128, C3 = 1024;
static constexpr int NBINS = 73;
static constexpr int NROWS = Bsz * C3;          // 16384
static constexpr int TOTAL = NBINS * NROWS;     // 1196032
static constexpr float VMINf = -10.0f;
static constexpr float TOTAL_MAXf = 327670.0f;  // 20*16384 - 10

typedef __attribute__((ext_vector_type(8))) short short8v;
typedef __attribute__((ext_vector_type(4))) float f32x4;

__device__ __forceinline__ float bnrelu(float x, float m, float inv, float g, float be) {
    float t = ((x - m) * inv) * g + be;
    return t > 0.0f ? t : 0.0f;
}

// fp32 -> bf16 round-to-nearest-even (bit formula, matches HW RNE)
__device__ __forceinline__ ushort f2bf(float f) {
    uint u = __float_as_uint(f);
    return (ushort)((u + 0x7FFFu + ((u >> 16) & 1u)) >> 16);
}

// XOR swizzle for 128-col bf16 LDS tiles: 16B-granular, kills row-stride bank conflicts (T2)
__device__ __forceinline__ int swz(int row, int col) {
    return row * 128 + (col ^ ((row & 7) << 3));
}

// ---------------- conv1: [16,3,2048] -> [16,64,2048] (pre-BN, bias added), float4 ----------------
__global__ __launch_bounds__(256)
void conv1_kernel(const float* __restrict__ x, const float* __restrict__ w,
                  const float* __restrict__ bias, float* __restrict__ out) {
    __shared__ float ws[C1 * 3];
    __shared__ float bs[C1];
    int tid = threadIdx.x;
    if (tid < C1 * 3) ws[tid] = w[tid];
    if (tid < C1) bs[tid] = bias[tid];
    __syncthreads();
    int p = blockIdx.x * 256 + tid;        // quad index, total 16*512 = 8192
    int b = p >> 9;
    int nq = p & 511;
    const float* xb = x + (size_t)b * 3 * Npts;
    float4 x0 = ((const float4*)xb)[nq];
    float4 x1 = ((const float4*)(xb + Npts))[nq];
    float4 x2 = ((const float4*)(xb + 2 * Npts))[nq];
    float* o = out + (size_t)b * C1 * Npts + nq * 4;
    #pragma unroll
    for (int c = 0; c < C1; ++c) {
        float w0 = ws[c * 3], w1 = ws[c * 3 + 1], w2 = ws[c * 3 + 2], bv = bs[c];
        float4 r;
        r.x = fmaf(w0, x0.x, fmaf(w1, x1.x, fmaf(w2, x2.x, bv)));
        r.y = fmaf(w0, x0.y, fmaf(w1, x1.y, fmaf(w2, x2.y, bv)));
        r.z = fmaf(w0, x0.z, fmaf(w1, x1.z, fmaf(w2, x2.z, bv)));
        r.w = fmaf(w0, x0.w, fmaf(w1, x1.w, fmaf(w2, x2.w, bv)));
        *(float4*)(o + (size_t)c * Npts) = r;
    }
}

// ---------------- partial stats for h1 (fp32): grid = C1*4 blocks, f64 atomics ----------------
__global__ __launch_bounds__(256)
void stats_partial_kernel(const float* __restrict__ in,
                          double* __restrict__ sum, double* __restrict__ sumsq) {
    int c = blockIdx.x >> 2;
    int qb = blockIdx.x & 3;
    int tid = threadIdx.x;
    double s = 0.0, q = 0.0;
    for (int bb = qb * 4; bb < qb * 4 + 4; ++bb) {
        const float4* p = (const float4*)(in + ((size_t)bb * C1 + c) * Npts);
        for (int n = tid; n < Npts / 4; n += 256) {
            float4 v = p[n];
            double a0 = v.x, a1 = v.y, a2 = v.z, a3 = v.w;
            s += a0 + a1 + a2 + a3;
            q += a0 * a0 + a1 * a1 + a2 * a2 + a3 * a3;
        }
    }
    __shared__ double sh_s[256];
    __shared__ double sh_q[256];
    sh_s[tid] = s; sh_q[tid] = q;
    __syncthreads();
    for (int off = 128; off > 0; off >>= 1) {
        if (tid < off) { sh_s[tid] += sh_s[tid + off]; sh_q[tid] += sh_q[tid + off]; }
        __syncthreads();
    }
    if (tid == 0) {
        unsafeAtomicAdd(&sum[c], sh_s[0]);
        unsafeAtomicAdd(&sumsq[c], sh_q[0]);
    }
}

// ---------------- stats for h3 (bf16): grid = C3*4 blocks, one row per pass ----------------
__global__ __launch_bounds__(256)
void stats3_bf16_kernel(const ushort* __restrict__ h3,
                        double* __restrict__ sum, double* __restrict__ sumsq) {
    int c = blockIdx.x >> 2;
    int qb = blockIdx.x & 3;
    int tid = threadIdx.x;
    double s = 0.0, q = 0.0;
    for (int bb = qb * 4; bb < qb * 4 + 4; ++bb) {
        const uint4* p = (const uint4*)(h3 + ((size_t)bb * C3 + c) * Npts);
        uint4 v = p[tid];                    // 256 threads x 16B = one 4KB row
        uint wv4[4] = {v.x, v.y, v.z, v.w};
        float fs = 0.f, fq = 0.f;
        #pragma unroll
        for (int j = 0; j < 4; ++j) {
            float lo = __uint_as_float(wv4[j] << 16);
            float hi = __uint_as_float(wv4[j] & 0xFFFF0000u);
            fs += lo + hi;
            fq += lo * lo + hi * hi;
        }
        s += (double)fs; q += (double)fq;
    }
    __shared__ double sh_s[256];
    __shared__ double sh_q[256];
    sh_s[tid] = s; sh_q[tid] = q;
    __syncthreads();
    for (int off = 128; off > 0; off >>= 1) {
        if (tid < off) { sh_s[tid] += sh_s[tid + off]; sh_q[tid] += sh_q[tid + off]; }
        __syncthreads();
    }
    if (tid == 0) {
        unsafeAtomicAdd(&sum[c], sh_s[0]);
        unsafeAtomicAdd(&sumsq[c], sh_q[0]);
    }
}

// ---------------- finalize: (sum, sumsq) -> (mean, rsqrt(var+eps)) ----------------
__global__ __launch_bounds__(256)
void finalize_stats_kernel(const double* __restrict__ s, const double* __restrict__ q, int C,
                           float* __restrict__ mout, float* __restrict__ iout) {
    int c = blockIdx.x * 256 + threadIdx.x;
    if (c >= C) return;
    double cnt = (double)Bsz * (double)Npts;
    double m = s[c] / cnt;
    double var = q[c] / cnt - m * m;
    mout[c] = (float)m;
    iout[c] = (float)(1.0 / sqrt(var + 1e-5));
}

// ---------------- 64x64 tiled conv2 (fp32), BN+ReLU on input, fused output stats ----------------
template<int CIN, int COUT>
__global__ __launch_bounds__(256)
void conv_bn_64(const float* __restrict__ in, const float* __restrict__ W,
                const float* __restrict__ bias,
                const float* __restrict__ m, const float* __restrict__ inv,
                const float* __restrict__ g, const float* __restrict__ be,
                float* __restrict__ out,
                double* __restrict__ sum, double* __restrict__ sumsq) {
    constexpr int KT = 32;
    __shared__ float Ws[KT][64];
    __shared__ float Xs[KT][64];
    int tid = threadIdx.x;
    int nBase = blockIdx.x * 64;
    int oBase = blockIdx.y * 64;
    int b = blockIdx.z;
    int ty = tid / 16, tx = tid % 16;
    float acc[4][4] = {};

    int w_o  = tid / 4;
    int w_k0 = (tid % 4) * 8;
    int x_c  = tid / 8;
    int x_n0 = (tid % 8) * 8;

    for (int kBase = 0; kBase < CIN; kBase += KT) {
        const float* wp = W + (size_t)(oBase + w_o) * CIN + kBase + w_k0;
        float4 wa = *(const float4*)wp;
        float4 wb = *(const float4*)(wp + 4);
        float wv[8] = {wa.x, wa.y, wa.z, wa.w, wb.x, wb.y, wb.z, wb.w};
        #pragma unroll
        for (int i = 0; i < 8; ++i) Ws[w_k0 + i][w_o] = wv[i];

        int c = kBase + x_c;
        float mm = m[c], ii = inv[c], gg = g[c], bb = be[c];
        const float* xp = in + ((size_t)b * CIN + c) * Npts + nBase + x_n0;
        float4 xa = *(const float4*)xp;
        float4 xb = *(const float4*)(xp + 4);
        float xv[8] = {xa.x, xa.y, xa.z, xa.w, xb.x, xb.y, xb.z, xb.w};
        #pragma unroll
        for (int i = 0; i < 8; ++i) Xs[x_c][x_n0 + i] = bnrelu(xv[i], mm, ii, gg, bb);

        __syncthreads();
        #pragma unroll
        for (int kk = 0; kk < KT; ++kk) {
            float4 w4 = *(const float4*)(&Ws[kk][ty * 4]);
            float4 x4 = *(const float4*)(&Xs[kk][tx * 4]);
            float wr[4] = {w4.x, w4.y, w4.z, w4.w};
            float xr[4] = {x4.x, x4.y, x4.z, x4.w};
            #pragma unroll
            for (int i = 0; i < 4; ++i)
                #pragma unroll
                for (int j = 0; j < 4; ++j)
                    acc[i][j] = fmaf(wr[i], xr[j], acc[i][j]);
        }
        __syncthreads();
    }

    #pragma unroll
    for (int i = 0; i < 4; ++i) {
        int o = oBase + ty * 4 + i;
        float bv = bias[o];
        float v[4] = {acc[i][0] + bv, acc[i][1] + bv, acc[i][2] + bv, acc[i][3] + bv};
        *(float4*)(out + ((size_t)b * COUT + o) * Npts + nBase + tx * 4) =
            make_float4(v[0], v[1], v[2], v[3]);
        double si = 0.0, qi = 0.0;
        #pragma unroll
        for (int j = 0; j < 4; ++j) { double dv = (double)v[j]; si += dv; qi += dv * dv; }
        #pragma unroll
        for (int off = 1; off < 16; off <<= 1) {
            si += __shfl_xor(si, off, 64);
            qi += __shfl_xor(qi, off, 64);
        }
        if (tx == 0) {
            unsafeAtomicAdd(&sum[o], si);
            unsafeAtomicAdd(&sumsq[o], qi);
        }
    }
}

// ---------------- h2 fp32 [b][c][n] -> h2t bf16 [b][n][c], applying bn2+relu ----------------
__global__ __launch_bounds__(256)
void transpose_bnrelu_kernel(const float* __restrict__ in,
                             const float* __restrict__ m, const float* __restrict__ inv,
                             const float* __restrict__ g, const float* __restrict__ be,
                             ushort* __restrict__ out) {
    __shared__ ushort Ls[C2 * 72];   // [c][n] tile, 64 n cols, pad to 72
    __shared__ float pm[C2], pi[C2], pg[C2], pb[C2];
    int tid = threadIdx.x;
    int n0 = blockIdx.x * 64;
    int b = blockIdx.y;
    if (tid < C2) { pm[tid] = m[tid]; pi[tid] = inv[tid]; pg[tid] = g[tid]; pb[tid] = be[tid]; }
    __syncthreads();
    #pragma unroll
    for (int it = 0; it < 8; ++it) {
        int q = it * 256 + tid;            // 2048 quads = 128c x 16 quad-cols
        int c = q >> 4, nq = q & 15;
        float4 v = *(const float4*)(in + ((size_t)b * C2 + c) * Npts + n0 + nq * 4);
        float mm = pm[c], ii = pi[c], gg = pg[c], bb = pb[c];
        uint lo = (uint)f2bf(bnrelu(v.x, mm, ii, gg, bb)) |
                  ((uint)f2bf(bnrelu(v.y, mm, ii, gg, bb)) << 16);
        uint hi = (uint)f2bf(bnrelu(v.z, mm, ii, gg, bb)) |
                  ((uint)f2bf(bnrelu(v.w, mm, ii, gg, bb)) << 16);
        *(uint2*)(&Ls[c * 72 + nq * 4]) = make_uint2(lo, hi);
    }
    __syncthreads();
    int n = tid >> 2, cs = (tid & 3) * 32;
    uint w[16];
    #pragma unroll
    for (int j = 0; j < 16; ++j) {
        w[j] = (uint)Ls[(cs + 2 * j) * 72 + n] | ((uint)Ls[(cs + 2 * j + 1) * 72 + n] << 16);
    }
    ushort* op = out + ((size_t)b * Npts + n0 + n) * C2 + cs;
    *(uint4*)(op)      = make_uint4(w[0],  w[1],  w[2],  w[3]);
    *(uint4*)(op + 8)  = make_uint4(w[4],  w[5],  w[6],  w[7]);
    *(uint4*)(op + 16) = make_uint4(w[8],  w[9],  w[10], w[11]);
    *(uint4*)(op + 24) = make_uint4(w[12], w[13], w[14], w[15]);
}

// ---------------- w3 fp32 [1024][128] -> bf16 (one-time) ----------------
__global__ __launch_bounds__(256)
void w3bf_kernel(const float* __restrict__ w, ushort* __restrict__ out) {
    int i = blockIdx.x * 256 + threadIdx.x;      // quad index, 32768 total
    float4 v = ((const float4*)w)[i];
    uint lo = (uint)f2bf(v.x) | ((uint)f2bf(v.y) << 16);
    uint hi = (uint)f2bf(v.z) | ((uint)f2bf(v.w) << 16);
    ((uint2*)out)[i] = make_uint2(lo, hi);
}

// ---------------- conv3 via bf16 MFMA: h2t[b][n][128] x w3bf[1024][128] -> h3 bf16 ----------------
// 128o x 128n block, K=128 single-shot. 4 waves 2x2 (each 64o x 64n, 64 MFMA).
// LDS: 2 x 32KB XOR-swizzled tiles (exactly 64KB). Epilogue: acc -> LDS (reuse Xl) -> 128B/thread
// coalesced stores. 16x16x32 layout [session-verified R10]: A row=l&15, k=(l>>4)*8+j;
// B col=l&15 same k; D col=l&15, row=(l>>4)*4+reg.
__global__ __launch_bounds__(256)
void conv3_mfma_kernel(const ushort* __restrict__ xt, const ushort* __restrict__ Wbf,
                       const float* __restrict__ bias, ushort* __restrict__ out) {
    __shared__ ushort Wl[128 * 128];          // 32 KB (swizzled)
    __shared__ ushort Xl[128 * 128];          // 32 KB (swizzled; reused for output tile)
    const int tid = threadIdx.x;
    const int nBase = blockIdx.x * 128;
    const int oBase = blockIdx.y * 128;
    const int b = blockIdx.z;

    const ushort* wb = Wbf + (size_t)oBase * C2;
    const ushort* xb = xt + ((size_t)b * Npts + nBase) * C2;
    #pragma unroll
    for (int it = 0; it < 8; ++it) {
        int o8 = it * 256 + tid;              // 2048 x 16B chunks per tile
        int r = o8 >> 4, c8 = (o8 & 15) * 8;
        *(uint4*)(&Wl[swz(r, c8)]) = *(const uint4*)(wb + (size_t)r * C2 + c8);
        *(uint4*)(&Xl[swz(r, c8)]) = *(const uint4*)(xb + (size_t)r * C2 + c8);
    }
    __syncthreads();

    const int wv = tid >> 6, lane = tid & 63, lr = lane & 15, lg = lane >> 4;
    const int wO = (wv >> 1) * 64, wN = (wv & 1) * 64;
    f32x4 acc[4][4];                           // [fo][nf]
    #pragma unroll
    for (int i = 0; i < 4; ++i)
        #pragma unroll
        for (int j = 0; j < 4; ++j) { f32x4 z = {0.f, 0.f, 0.f, 0.f}; acc[i][j] = z; }

    #pragma unroll
    for (int ks = 0; ks < 4; ++ks) {
        const int ko = ks * 32 + lg * 8;
        short8v afr[4], bfr[4];
        #pragma unroll
        for (int fo = 0; fo < 4; ++fo)
            afr[fo] = *(const short8v*)(&Wl[swz(wO + fo * 16 + lr, ko)]);
        #pragma unroll
        for (int nf = 0; nf < 4; ++nf)
            bfr[nf] = *(const short8v*)(&Xl[swz(wN + nf * 16 + lr, ko)]);
        #pragma unroll
        for (int fo = 0; fo < 4; ++fo)
            #pragma unroll
            for (int nf = 0; nf < 4; ++nf)
                acc[fo][nf] = __builtin_amdgcn_mfma_f32_16x16x32_bf16(
                    afr[fo], bfr[nf], acc[fo][nf], 0, 0, 0);
    }
    __syncthreads();                           // X consumed; reuse Xl as output tile

    #pragma unroll
    for (int fo = 0; fo < 4; ++fo) {
        #pragma unroll
        for (int rg = 0; rg < 4; ++rg) {
            int olc = wO + fo * 16 + lg * 4 + rg;
            float bv = bias[oBase + olc];
            #pragma unroll
            for (int nf = 0; nf < 4; ++nf)
                Xl[swz(olc, wN + nf * 16 + lr)] = f2bf(acc[fo][nf][rg] + bv);
        }
    }
    __syncthreads();

    // coalesced store: thread -> (row r, half hh) = 64 bf16 = 128B contiguous
    int r = tid >> 1, hh = (tid & 1) * 64;
    ushort* op = out + ((size_t)b * C3 + oBase + r) * Npts + nBase + hh;
    #pragma unroll
    for (int j = 0; j < 8; ++j)
        *(uint4*)(op + j * 8) = *(const uint4*)(&Xl[swz(r, hh + j * 8)]);
}

// ---------------- histogram (bf16 input): wave-private bins, lazy zero counting ----------------
__global__ __launch_bounds__(256)
void hist_kernel(const ushort* __restrict__ h3,
                 const float* __restrict__ m, const float* __restrict__ inv,
                 const float* __restrict__ g, const float* __restrict__ be,
                 unsigned* __restrict__ counts) {
    __shared__ unsigned bins[4][80];
    int row = blockIdx.x;                   // b*C3 + f
    int f = row & (C3 - 1);
    int tid = threadIdx.x;
    int wv = tid >> 6;
    for (int i = tid; i < 4 * 80; i += 256) ((unsigned*)bins)[i] = 0u;
    __syncthreads();
    float mm = m[f], ii = inv[f], gg = g[f], bb = be[f];
    float off = 20.0f * (float)row;
    const uint4* p4 = (const uint4*)(h3 + (size_t)row * Npts);
    const float WIDTH = (float)(327680.0 / 1196032.0);
    int rbase = row * NBINS;
    int zc = 0;
    uint4 q = p4[tid];                      // 8 bf16 per thread, single pass
    uint wsv[4] = {q.x, q.y, q.z, q.w};
    #pragma unroll
    for (int j = 0; j < 4; ++j) {
        float vlo = __uint_as_float(wsv[j] << 16);
        float vhi = __uint_as_float(wsv[j] & 0xFFFF0000u);
        float pair[2] = {vlo, vhi};
        #pragma unroll
        for (int h = 0; h < 2; ++h) {
            float v = bnrelu(pair[h], mm, ii, gg, bb);
            if (v == 0.0f) { ++zc; continue; }
            float flat = v + off;
            if (flat >= VMINf && flat <= TOTAL_MAXf) {
                int idx = (int)floorf((flat - VMINf) / WIDTH);
                if (idx > TOTAL - 1) idx = TOTAL - 1;
                if (idx < 0) idx = 0;
                int local = idx - rbase;
                if (local >= 0 && local < NBINS) atomicAdd(&bins[wv][local], 1u);
                else atomicAdd(&counts[idx], 1u);
            }
        }
    }
    #pragma unroll
    for (int o = 32; o >= 1; o >>= 1) zc += __shfl_xor(zc, o, 64);
    if ((tid & 63) == 0 && zc) atomicAdd(&bins[wv][36], (unsigned)zc);
    __syncthreads();
    if (tid < NBINS) {
        unsigned t = bins[0][tid] + bins[1][tid] + bins[2][tid] + bins[3][tid];
        if (t) atomicAdd(&counts[rbase + tid], t);
    }
}

// ---------------- per-row first-max argmax -> feat ----------------
__global__ __launch_bounds__(256)
void argmax_kernel(const unsigned* __restrict__ counts, float* __restrict__ feat) {
    int row = blockIdx.x * 256 + threadIdx.x;
    if (row >= NROWS) return;
    const unsigned* c = counts + (size_t)row * NBINS;
    unsigned best = c[0]; int bi = 0;
    #pragma unroll 8
    for (int i = 1; i < NBINS; ++i) {
        unsigned v = c[i];
        if (v > best) { best = v; bi = i; }
    }
    feat[row] = (float)bi;
}

// ---------------- FC + batch-BN + ReLU (one block per output feature) ----------------
template<int K, int COUT>
__global__ __launch_bounds__(256)
void fc_bn_relu_kernel(const float* __restrict__ in, const float* __restrict__ W,
                       const float* __restrict__ bias,
                       const float* __restrict__ g, const float* __restrict__ be,
                       float* __restrict__ out) {
    int j = blockIdx.x;
    int tid = threadIdx.x;
    int b = tid / 16;
    int l = tid % 16;
    const float* wrow = W + (size_t)j * K;
    const float* xrow = in + (size_t)b * K;
    float s = 0.0f;
    for (int k = l; k < K; k += 16) s = fmaf(xrow[k], wrow[k], s);
    #pragma unroll
    for (int o = 8; o >= 1; o >>= 1) s += __shfl_xor(s, o, 64);
    __shared__ float vals[Bsz];
    __shared__ float stat[2];
    if (l == 0) vals[b] = s + bias[j];
    __syncthreads();
    if (tid == 0) {
        double a = 0.0, q = 0.0;
        for (int i = 0; i < Bsz; ++i) { double v = vals[i]; a += v; q += v * v; }
        double mm = a / Bsz;
        double var = q / Bsz - mm * mm;
        stat[0] = (float)mm;
        stat[1] = (float)(1.0 / sqrt(var + 1e-5));
    }
    __syncthreads();
    if (tid < Bsz) {
        float t = ((vals[tid] - stat[0]) * stat[1]) * g[j] + be[j];
        out[(size_t)tid * COUT + j] = t > 0.0f ? t : 0.0f;
    }
}

// ---------------- fc3 + identity ----------------
__global__ __launch_bounds__(256)
void fc3_kernel(const float* __restrict__ in, const float* __restrict__ W,
                const float* __restrict__ bias, float* __restrict__ out) {
    int t = threadIdx.x;
    if (t >= Bsz * 9) return;
    int b = t / 9, j = t % 9;
    const float* x = in + (size_t)b * 256;
    const float* w = W + (size_t)j * 256;
    float s = 0.0f;
    for (int k = 0; k < 256; ++k) s = fmaf(x[k], w[k], s);
    s += bias[j];
    if (j == 0 || j == 4 || j == 8) s += 1.0f;
    out[t] = s;
}

extern "C" void kernel_launch(void* const* d_in, const int* in_sizes, int n_in,
                              void* d_out, int out_size, void* d_ws, size_t ws_size,
                              hipStream_t stream) {
    const float* x   = (const float*)d_in[0];
    const float* w1  = (const float*)d_in[1];
    const float* b1  = (const float*)d_in[2];
    const float* g1  = (const float*)d_in[3];
    const float* be1 = (const float*)d_in[4];
    const float* w2  = (const float*)d_in[5];
    const float* b2  = (const float*)d_in[6];
    const float* g2  = (const float*)d_in[7];
    const float* be2 = (const float*)d_in[8];
    const float* w3  = (const float*)d_in[9];
    const float* b3  = (const float*)d_in[10];
    const float* g3  = (const float*)d_in[11];
    const float* be3 = (const float*)d_in[12];
    const float* fw1 = (const float*)d_in[13];
    const float* fb1 = (const float*)d_in[14];
    const float* g4  = (const float*)d_in[15];
    const float* be4 = (const float*)d_in[16];
    const float* fw2 = (const float*)d_in[17];
    const float* fb2 = (const float*)d_in[18];
    const float* g5  = (const float*)d_in[19];
    const float* be5 = (const float*)d_in[20];
    const float* fw3 = (const float*)d_in[21];
    const float* fb3 = (const float*)d_in[22];

    // workspace: [f64 accumulators][u32 counts][f32 tensors][bf16 tensors]
    double* sum1 = (double*)d_ws;                       // 64
    double* q1d  = sum1 + C1;
    double* sum2 = q1d + C1;                            // 128
    double* q2   = sum2 + C2;
    double* sum3 = q2 + C2;                             // 1024
    double* q3   = sum3 + C3;
    unsigned* counts = (unsigned*)(q3 + C3);            // 1,196,032
    float* h1 = (float*)(counts + TOTAL);               // 16*64*2048 f32
    float* h2 = h1 + (size_t)Bsz * C1 * Npts;           // 16*128*2048 f32
    float* m1 = h2 + (size_t)Bsz * C2 * Npts;
    float* i1 = m1 + C1;
    float* m2 = i1 + C1;
    float* i2 = m2 + C2;
    float* m3 = i2 + C2;
    float* i3 = m3 + C3;
    float* feat = i3 + C3;                              // 16,384
    float* h4 = feat + NROWS;
    float* h5 = h4 + Bsz * 512;
    ushort* h2t = (ushort*)(h5 + Bsz * 256);            // 16*2048*128 bf16
    ushort* h3  = h2t + (size_t)Bsz * Npts * C2;        // 16*1024*2048 bf16
    ushort* w3bf = h3 + (size_t)Bsz * C3 * Npts;        // 1024*128 bf16

    size_t zero_bytes = (size_t)(2 * C1 + 2 * C2 + 2 * C3) * sizeof(double)
                      + (size_t)TOTAL * sizeof(unsigned);
    hipMemsetAsync(d_ws, 0, zero_bytes, stream);

    conv1_kernel<<<dim3(Bsz * Npts / 4 / 256), 256, 0, stream>>>(x, w1, b1, h1);
    stats_partial_kernel<<<dim3(C1 * 4), 256, 0, stream>>>(h1, sum1, q1d);
    finalize_stats_kernel<<<dim3(1), 256, 0, stream>>>(sum1, q1d, C1, m1, i1);
    conv_bn_64<C1, C2><<<dim3(Npts / 64, C2 / 64, Bsz), 256, 0, stream>>>(
        h1, w2, b2, m1, i1, g1, be1, h2, sum2, q2);
    finalize_stats_kernel<<<dim3(1), 256, 0, stream>>>(sum2, q2, C2, m2, i2);
    transpose_bnrelu_kernel<<<dim3(Npts / 64, Bsz), 256, 0, stream>>>(
        h2, m2, i2, g2, be2, h2t);
    w3bf_kernel<<<dim3(C3 * C2 / 4 / 256), 256, 0, stream>>>(w3, w3bf);
    conv3_mfma_kernel<<<dim3(Npts / 128, C3 / 128, Bsz), 256, 0, stream>>>(
        h2t, w3bf, b3, h3);
    stats3_bf16_kernel<<<dim3(C3 * 4), 256, 0, stream>>>(h3, sum3, q3);
    finalize_stats_kernel<<<dim3(C3 / 256), 256, 0, stream>>>(sum3, q3, C3, m3, i3);
    hist_kernel<<<dim3(NROWS), 256, 0, stream>>>(h3, m3, i3, g3, be3, counts);
    argmax_kernel<<<dim3(NROWS / 256), 256, 0, stream>>>(counts, feat);
    fc_bn_relu_kernel<1024, 512><<<dim3(512), 256, 0, stream>>>(feat, fw1, fb1, g4, be4, h4);
    fc_bn_relu_kernel<512, 256><<<dim3(256), 256, 0, stream>>>(h4, fw2, fb2, g5, be5, h5);
    fc3_kernel<<<dim3(1), 256, 0, stream>>>(h5, fw3, fb3, (float*)d_out);
}